// Round 6
// baseline (7622.477 us; speedup 1.0000x reference)
//
#include <hip/hip_runtime.h>
#include <stdint.h>

// R6: controlled experiment on the R2 skeleton (best verified: 1315 us).
// Changes vs R2 (ONLY these):
//  - per-block weight-stream decorrelation: 3-phase kt rotation (33 = 3 x 11)
//    + jt order parity. All blocks on an XCD otherwise read identical
//    addresses in near-lockstep -> suspected L2 same-line contention.
//  - fully unrolled 11-kt chunks (R2 had unroll 3) -> deeper load hoisting.
// Everything else byte-identical to R2 (LDS layout, register shape, heads).
// R4/R5 lesson: M=64/block needs ~230 live VGPRs -> allocator spills ->
// scratch evicts weights from L2 -> GBs of HBM traffic. Do not retry as-is.

#define H 512
#define KAUG 528
#define KT_N 33            // K tiles of 16 (528/16)
#define LROW 536           // LDS row stride in shorts (R2-proven ~0 conflicts)
#define NROW 32
#define WMAT_ELEMS (16 * KT_N * 4 * 512)   // 1,081,344 shorts per matrix
#define T_DEC 32
#define B_TOT 4096

typedef __attribute__((ext_vector_type(8))) short short8;
typedef __attribute__((ext_vector_type(16))) float floatx16;

__device__ __forceinline__ unsigned short f2bf(float x) {
  union { float f; unsigned int u; } v; v.f = x;
  unsigned int u = v.u;
  return (unsigned short)((u + 0x7FFFu + ((u >> 16) & 1u)) >> 16);
}
__device__ __forceinline__ float bf2f(unsigned short s) {
  union { unsigned int u; float f; } v; v.u = ((unsigned int)s) << 16;
  return v.f;
}
__device__ __forceinline__ float rcpf(float x) { return __builtin_amdgcn_rcpf(x); }
__device__ __forceinline__ float sigm(float x) { return rcpf(1.0f + __expf(-x)); }
__device__ __forceinline__ float tanh_f(float x) {
  return 1.0f - 2.0f * rcpf(1.0f + __expf(2.0f * x));
}

// ---------------- prep: identical to R2 --------------------------------------
__global__ void prep_weights(
    const float* __restrict__ Wh_s, const float* __restrict__ Wi_s, const float* __restrict__ b_s,
    const float* __restrict__ Wh_p, const float* __restrict__ Wi_p, const float* __restrict__ b_p,
    const float* __restrict__ Wh_d, const float* __restrict__ Wi_d, const float* __restrict__ b_d,
    const float* __restrict__ Wh_i, const float* __restrict__ Wi_i, const float* __restrict__ b_i,
    short* __restrict__ wpack)
{
  int idx = blockIdx.x * 256 + threadIdx.x;
  const int per = 2048 * KAUG;
  if (idx >= 4 * per) return;
  int mat = idx / per;
  int rem = idx - mat * per;
  int n = rem / KAUG;
  int ka = rem - n * KAUG;
  const float* Wh; const float* Wi; const float* bb;
  if (mat == 0)      { Wh = Wh_s; Wi = Wi_s; bb = b_s; }
  else if (mat == 1) { Wh = Wh_p; Wi = Wi_p; bb = b_p; }
  else if (mat == 2) { Wh = Wh_d; Wi = Wi_d; bb = b_d; }
  else               { Wh = Wh_i; Wi = Wi_i; bb = b_i; }
  float v;
  if (ka < 512)      v = Wh[n * 512 + ka];
  else if (ka < 516) v = Wi[n * 4 + (ka - 512)];
  else if (ka == 516) v = bb[n];
  else               v = 0.0f;
  int g = n >> 9, ntL = (n >> 5) & 15, ni = n & 31;
  int kt = ka >> 4, kh = (ka >> 3) & 1, ks = ka & 7;
  int lanep = kh * 32 + ni;
  wpack[(size_t)mat * WMAT_ELEMS +
        (((((size_t)ntL * KT_N + kt) * 4 + g) << 9) + (lanep << 3) + ks)] = (short)f2bf(v);
}

// ---------------- one 11-kt chunk, fully unrolled ----------------------------
template<int KT0>
__device__ __forceinline__ void gate_chunk(
    const short* aptr, const short* __restrict__ bpg,
    floatx16& ai, floatx16& af, floatx16& ag, floatx16& ao)
{
  const short* bp = bpg + KT0 * 2048;
  #pragma unroll
  for (int k = 0; k < 11; ++k) {
    int kt = KT0 + k;
    short8 a  = *(const short8*)(aptr + kt * 16);
    short8 b0 = *(const short8*)(bp);
    short8 b1 = *(const short8*)(bp + 512);
    short8 b2 = *(const short8*)(bp + 1024);
    short8 b3 = *(const short8*)(bp + 1536);
    bp += 2048;
    ai = __builtin_amdgcn_mfma_f32_32x32x16_bf16(a, b0, ai, 0, 0, 0);
    af = __builtin_amdgcn_mfma_f32_32x32x16_bf16(a, b1, af, 0, 0, 0);
    ag = __builtin_amdgcn_mfma_f32_32x32x16_bf16(a, b2, ag, 0, 0, 0);
    ao = __builtin_amdgcn_mfma_f32_32x32x16_bf16(a, b3, ao, 0, 0, 0);
  }
}

// ---------------- one LSTM step (pass jt, phase-rotated kt) ------------------
__device__ __forceinline__ void lstm_step_mfma(
    const short* hl, const short* __restrict__ wm,
    int lane, int wv, int jpar, int ph, float c_reg[2][16], float hnew[2][16])
{
  int arow = lane & 31, ahalf = lane >> 5;
  const short* aptr = hl + arow * LROW + ahalf * 8;
  #pragma unroll
  for (int jt = 0; jt < 2; ++jt) {
    int ntL = wv * 2 + (jt ^ jpar);
    const short* bpg = wm + (size_t)ntL * (KT_N * 2048) + (lane << 3);
    floatx16 ai = (floatx16)0.0f, af = (floatx16)0.0f,
             ag = (floatx16)0.0f, ao = (floatx16)0.0f;
    if (ph == 0) {
      gate_chunk<0>(aptr, bpg, ai, af, ag, ao);
      gate_chunk<11>(aptr, bpg, ai, af, ag, ao);
      gate_chunk<22>(aptr, bpg, ai, af, ag, ao);
    } else if (ph == 1) {
      gate_chunk<11>(aptr, bpg, ai, af, ag, ao);
      gate_chunk<22>(aptr, bpg, ai, af, ag, ao);
      gate_chunk<0>(aptr, bpg, ai, af, ag, ao);
    } else {
      gate_chunk<22>(aptr, bpg, ai, af, ag, ao);
      gate_chunk<0>(aptr, bpg, ai, af, ag, ao);
      gate_chunk<11>(aptr, bpg, ai, af, ag, ao);
    }
    #pragma unroll
    for (int r = 0; r < 16; ++r) {
      float si = sigm(ai[r]);
      float sf = sigm(af[r]);
      float tg = tanh_f(ag[r]);
      float so = sigm(ao[r]);
      float cn = sf * c_reg[jt][r] + si * tg;
      c_reg[jt][r] = cn;
      hnew[jt][r] = so * tanh_f(cn);
    }
  }
}

__device__ __forceinline__ void write_h(short* hl, int lane, int wv, int jpar,
                                        const float hnew[2][16]) {
  int arow = lane & 31, ahalf = lane >> 5;
  #pragma unroll
  for (int jt = 0; jt < 2; ++jt) {
    int col = (wv * 2 + (jt ^ jpar)) * 32 + arow;
    #pragma unroll
    for (int r = 0; r < 16; ++r) {
      int row = (r & 3) + ((r >> 2) << 3) + (ahalf << 2);
      hl[row * LROW + col] = (short)f2bf(hnew[jt][r]);
    }
  }
}

// ---------------- encoder ----------------------------------------------------
__global__ __launch_bounds__(512) void lstm_encoder(
    const float* __restrict__ speed, const float* __restrict__ pos,
    const short* __restrict__ wpack,
    short* __restrict__ h_enc, float* __restrict__ c_enc)
{
  __shared__ short hl[NROW * LROW];
  int tid = threadIdx.x;
  int b = blockIdx.x;
  int xcd = b & 7, slot = b >> 3;
  int enc = xcd >> 2;               // XCDs 0-3: speed, 4-7: pos (L2 locality)
  int rg = slot * 4 + (xcd & 3);    // 0..127
  int r0 = rg * 32;
  int jpar = slot & 1;
  int ph = (slot >> 1) % 3;
  const float* xin = enc ? pos : speed;
  const short* wm = wpack + (size_t)enc * WMAT_ELEMS;

  for (int i = tid; i < NROW * LROW; i += 512) hl[i] = 0;
  __syncthreads();
  if (tid < 32) hl[tid * LROW + 516] = (short)0x3F80;   // bias lane = 1.0
  if (tid < 128) {
    int r = tid >> 2, c = tid & 3;
    hl[r * LROW + 512 + c] = (short)f2bf(xin[(r0 + r) * 64 + c]);   // x_0
  }
  __syncthreads();

  int lane = tid & 63, wv = tid >> 6;
  float c_reg[2][16];
  #pragma unroll
  for (int jt = 0; jt < 2; ++jt)
    #pragma unroll
    for (int r = 0; r < 16; ++r) c_reg[jt][r] = 0.0f;
  float hnew[2][16];

  for (int t = 0; t < 16; ++t) {
    lstm_step_mfma(hl, wm, lane, wv, jpar, ph, c_reg, hnew);
    __syncthreads();
    write_h(hl, lane, wv, jpar, hnew);
    if (t < 15 && tid < 128) {
      int r = tid >> 2, c = tid & 3;
      hl[r * LROW + 512 + c] = (short)f2bf(xin[(r0 + r) * 64 + (t + 1) * 4 + c]);
    }
    __syncthreads();
  }

  // store h (bf16) + c (fp32) for the decoder
  for (int i = tid; i < 32 * 512; i += 512) {
    int r = i >> 9, k = i & 511;
    h_enc[((size_t)(enc * B_TOT + r0 + r) << 9) + k] = hl[r * LROW + k];
  }
  int arow = lane & 31, ahalf = lane >> 5;
  #pragma unroll
  for (int jt = 0; jt < 2; ++jt) {
    int col = (wv * 2 + (jt ^ jpar)) * 32 + arow;
    #pragma unroll
    for (int r = 0; r < 16; ++r) {
      int row = (r & 3) + ((r >> 2) << 3) + (ahalf << 2);
      c_enc[((size_t)(enc * B_TOT + r0 + row) << 9) + col] = c_reg[jt][r];
    }
  }
}

// ---------------- decoder ----------------------------------------------------
__global__ __launch_bounds__(512) void lstm_decoder(
    const float* __restrict__ speed, const float* __restrict__ pos,
    const short* __restrict__ wpack,
    const short* __restrict__ h_enc, const float* __restrict__ c_enc,
    const float* __restrict__ W_fs, const float* __restrict__ b_fs,
    const float* __restrict__ W_fc, const float* __restrict__ b_fc,
    const float* __restrict__ W_emb, const float* __restrict__ b_emb,
    float* __restrict__ out)
{
  __shared__ short hl[NROW * LROW];
  int tid = threadIdx.x;
  int b = blockIdx.x;
  int xcd = b & 7, slot = b >> 3;
  int chain = xcd >> 2;
  int rg = slot * 4 + (xcd & 3);
  int r0 = rg * 32;
  int jpar = slot & 1;
  int ph = (slot >> 1) % 3;
  const short* wm = wpack + (size_t)(2 + chain) * WMAT_ELEMS;

  for (int i = tid; i < NROW * LROW; i += 512) hl[i] = 0;
  __syncthreads();
  for (int i = tid; i < 32 * 512; i += 512) {
    int r = i >> 9, k = i & 511;
    float h0 = bf2f((unsigned short)h_enc[((size_t)(r0 + r) << 9) + k])
             + bf2f((unsigned short)h_enc[((size_t)(B_TOT + r0 + r) << 9) + k]);
    hl[r * LROW + k] = (short)f2bf(h0);
  }
  if (tid < 32) hl[tid * LROW + 516] = (short)0x3F80;
  {
    const float* last = chain ? pos : speed;
    if (tid < 128) {
      int r = tid >> 2, c = tid & 3;
      hl[r * LROW + 512 + c] = (short)f2bf(last[(r0 + r) * 64 + 60 + c]); // x[:,15,:]
    }
  }
  int lane = tid & 63, wv = tid >> 6;
  int arow = lane & 31, ahalf = lane >> 5;
  float c_reg[2][16];
  #pragma unroll
  for (int jt = 0; jt < 2; ++jt) {
    int col = (wv * 2 + (jt ^ jpar)) * 32 + arow;
    #pragma unroll
    for (int r = 0; r < 16; ++r) {
      int row = (r & 3) + ((r >> 2) << 3) + (ahalf << 2);
      size_t gi = ((size_t)(r0 + row) << 9) + col;
      c_reg[jt][r] = c_enc[gi] + c_enc[gi + (((size_t)B_TOT) << 9)];
    }
  }
  __syncthreads();

  float hnew[2][16];
  for (int t = 0; t < T_DEC; ++t) {
    lstm_step_mfma(hl, wm, lane, wv, jpar, ph, c_reg, hnew);
    __syncthreads();
    write_h(hl, lane, wv, jpar, hnew);
    __syncthreads();
    // heads: wave wv handles rows [wv*4, wv*4+4); 64 lanes x 8 k-elems = 512
    #pragma unroll 1
    for (int r = 0; r < 4; ++r) {
      int row = wv * 4 + r;
      const short8 hvs = *(const short8*)(hl + row * LROW + lane * 8);
      float hv[8];
      #pragma unroll
      for (int j = 0; j < 8; ++j) hv[j] = bf2f((unsigned short)hvs[j]);
      if (chain == 0) {
        float p0 = 0.f, p1 = 0.f, p2 = 0.f, p3 = 0.f;
        #pragma unroll
        for (int j = 0; j < 8; ++j) {
          p0 += hv[j] * W_fs[0 * 512 + lane * 8 + j];
          p1 += hv[j] * W_fs[1 * 512 + lane * 8 + j];
          p2 += hv[j] * W_fs[2 * 512 + lane * 8 + j];
          p3 += hv[j] * W_fs[3 * 512 + lane * 8 + j];
        }
        #pragma unroll
        for (int off = 32; off > 0; off >>= 1) {
          p0 += __shfl_xor(p0, off);
          p1 += __shfl_xor(p1, off);
          p2 += __shfl_xor(p2, off);
          p3 += __shfl_xor(p3, off);
        }
        float s0 = fminf(fmaxf(p0 + b_fs[0], -100.0f), 100.0f);
        float s1 = fminf(fmaxf(p1 + b_fs[1], -100.0f), 100.0f);
        float s2 = fminf(fmaxf(p2 + b_fs[2], -100.0f), 100.0f);
        float s3 = fminf(fmaxf(p3 + b_fs[3], -100.0f), 100.0f);
        if (lane < 4) {
          float v = (lane == 0) ? s0 : (lane == 1) ? s1 : (lane == 2) ? s2 : s3;
          out[(size_t)(r0 + row) * 128 + t * 4 + lane] = v;       // speed_outputs
          hl[row * LROW + 512 + lane] = (short)f2bf(v);           // ls feedback
        }
      } else {
        float p0 = 0.f, p1 = 0.f;
        #pragma unroll
        for (int j = 0; j < 8; ++j) {
          p0 += hv[j] * W_fc[0 * 512 + lane * 8 + j];
          p1 += hv[j] * W_fc[1 * 512 + lane * 8 + j];
        }
        #pragma unroll
        for (int off = 32; off > 0; off >>= 1) {
          p0 += __shfl_xor(p0, off);
          p1 += __shfl_xor(p1, off);
        }
        float it0 = fmaxf(p0 + b_fc[0], 0.0f);
        float it1 = fmaxf(p1 + b_fc[1], 0.0f);
        if (lane < 4) {
          float lp = fmaxf(W_emb[lane * 2] * it0 + W_emb[lane * 2 + 1] * it1 + b_emb[lane], 0.0f);
          hl[row * LROW + 512 + lane] = (short)f2bf(lp);          // lp feedback
        }
        if (t == T_DEC - 1 && lane < 2) {
          float m = fmaxf(it0, it1);
          float e0 = __expf(it0 - m), e1 = __expf(it1 - m);
          float v = ((lane == 0) ? e0 : e1) * rcpf(e0 + e1);
          out[(size_t)524288 + (size_t)(r0 + row) * 2 + lane] = v; // crossing
        }
      }
    }
    __syncthreads();
  }
}

extern "C" void kernel_launch(void* const* d_in, const int* in_sizes, int n_in,
                              void* d_out, int out_size, void* d_ws, size_t ws_size,
                              hipStream_t stream)
{
  const float* speed    = (const float*)d_in[0];
  const float* pos      = (const float*)d_in[1];
  const float* enc_s_Wi = (const float*)d_in[2];
  const float* enc_s_Wh = (const float*)d_in[3];
  const float* enc_s_b  = (const float*)d_in[4];
  const float* enc_p_Wi = (const float*)d_in[5];
  const float* enc_p_Wh = (const float*)d_in[6];
  const float* enc_p_b  = (const float*)d_in[7];
  const float* dec_s_Wi = (const float*)d_in[8];
  const float* dec_s_Wh = (const float*)d_in[9];
  const float* dec_s_b  = (const float*)d_in[10];
  const float* dec_i_Wi = (const float*)d_in[11];
  const float* dec_i_Wh = (const float*)d_in[12];
  const float* dec_i_b  = (const float*)d_in[13];
  const float* W_fs     = (const float*)d_in[14];
  const float* b_fs     = (const float*)d_in[15];
  const float* W_fc     = (const float*)d_in[16];
  const float* b_fc     = (const float*)d_in[17];
  const float* W_emb    = (const float*)d_in[18];
  const float* b_emb    = (const float*)d_in[19];
  float* out = (float*)d_out;

  char* ws = (char*)d_ws;
  short* wpack = (short*)ws;                 // 4 x 2,162,688 B = 8,650,752 B
  short* h_enc = (short*)(ws + 8650752);     // 2 x 4096 x 512 bf16 = 8,388,608 B
  float* c_enc = (float*)(ws + 17039360);    // 2 x 4096 x 512 f32  = 16,777,216 B

  prep_weights<<<16896, 256, 0, stream>>>(
      enc_s_Wh, enc_s_Wi, enc_s_b,
      enc_p_Wh, enc_p_Wi, enc_p_b,
      dec_s_Wh, dec_s_Wi, dec_s_b,
      dec_i_Wh, dec_i_Wi, dec_i_b,
      wpack);
  lstm_encoder<<<256, 512, 0, stream>>>(speed, pos, wpack, h_enc, c_enc);
  lstm_decoder<<<256, 512, 0, stream>>>(speed, pos, wpack, h_enc, c_enc,
                                        W_fs, b_fs, W_fc, b_fc, W_emb, b_emb, out);
}

// Round 7
// 4187.704 us; speedup vs baseline: 1.8202x; 1.8202x over previous
//
#include <hip/hip_runtime.h>
#include <stdint.h>

// R7: weight-stationary dataflow. Weights pinned in LDS (131 KB/block, read via
// ds_read, NEVER through L2 after the one-time fill) -> the per-step L2
// acquire-invalidate (R3's poison) only costs re-reading the small h-exchange,
// which is mandatory traffic anyway. h (512 KB/group/step) moves through L3
// instead of 2.16 MB of weights through L1 per CU per step (R2's 14.1 us/step
// floor). 256 blocks = 1/CU, all co-resident; 16 blocks/group sync via
// release/acquire flags (guard-capped spins; flags re-zeroed by prep each call).
// Spill discipline (R4/R5/R6): one M-pass of acc (64 VGPR) live at a time,
// unroll<=8, every reg-array index compile-time constant.

#define WSLICE 65536              // shorts per (mat, j) weight slice
#define HX_PAR 262144             // shorts per parity buffer (32 kchunk x 512 row x 16)
#define HX_SLOT (2 * HX_PAR)      // shorts per slot
#define GUARD (1L << 22)

typedef __attribute__((ext_vector_type(8))) short short8;
typedef __attribute__((ext_vector_type(16))) float floatx16;

__device__ __forceinline__ unsigned short f2bf(float x) {
  union { float f; unsigned int u; } v; v.f = x;
  unsigned int u = v.u;
  return (unsigned short)((u + 0x7FFFu + ((u >> 16) & 1u)) >> 16);
}
__device__ __forceinline__ float bf2f(unsigned short s) {
  union { unsigned int u; float f; } v; v.u = ((unsigned int)s) << 16;
  return v.f;
}
__device__ __forceinline__ float rcpf(float x) { return __builtin_amdgcn_rcpf(x); }
__device__ __forceinline__ float sigm(float x) { return rcpf(1.0f + __expf(-x)); }
__device__ __forceinline__ float tanh_f(float x) {
  return 1.0f - 2.0f * rcpf(1.0f + __expf(2.0f * x));
}

// ---------------- prep: pack Wh slices (B-frag layout) + zero flags ----------
__global__ void prep_weights(
    const float* __restrict__ Wh_s, const float* __restrict__ Wh_p,
    const float* __restrict__ Wh_d, const float* __restrict__ Wh_i,
    short* __restrict__ wpack, int* __restrict__ flags)
{
  int idx = blockIdx.x * 256 + threadIdx.x;
  if (idx < 1024) flags[idx] = 0;
  if (idx >= 4 * 1048576) return;
  int mat = idx >> 20;
  int rem = idx & 1048575;
  int n = rem >> 9, ka = rem & 511;
  const float* Wh = (mat == 0) ? Wh_s : (mat == 1) ? Wh_p : (mat == 2) ? Wh_d : Wh_i;
  float v = Wh[n * 512 + ka];
  int gate = n >> 9, j = (n >> 5) & 15, ni = n & 31;
  int kt = ka >> 4, kh = (ka >> 3) & 1, ks = ka & 7;
  int lane = kh * 32 + ni;
  wpack[(size_t)(mat * 16 + j) * WSLICE + ((gate * 32 + kt) * 64 + lane) * 8 + ks] =
      (short)f2bf(v);
}

// ---------------- sync helpers ----------------------------------------------
__device__ __forceinline__ void waitall(int* f, int v, int tid) {
  if (tid == 0) {
    #pragma unroll 1
    for (int i = 0; i < 16; ++i) {
      long g = 0;
      while (__hip_atomic_load(f + i, __ATOMIC_ACQUIRE, __HIP_MEMORY_SCOPE_AGENT) < v) {
        __builtin_amdgcn_s_sleep(2);
        if (++g > GUARD) break;       // safety: never hang the queue
      }
    }
  }
  __syncthreads();
}
__device__ __forceinline__ void postflag(int* fp, int v, int tid) {
  __syncthreads();                    // all waves' stores drained (vmcnt(0) at barrier)
  if (tid == 0)
    __hip_atomic_store(fp, v, __ATOMIC_RELEASE, __HIP_MEMORY_SCOPE_AGENT);
}

// ---------------- K pass: 32 rows x 128 gate-cols, K=512 --------------------
// acur: parity base + (rowbase + (lane&31))*16 + (lane>>5)*8
// wl:   wlds + lane*8
__device__ __forceinline__ void kpass(const short* wl, const short* acur,
                                      floatx16 (&acc)[4])
{
  floatx16 a0 = (floatx16)0.0f, a1 = (floatx16)0.0f,
           a2 = (floatx16)0.0f, a3 = (floatx16)0.0f;
  #pragma unroll 8
  for (int kt = 0; kt < 32; ++kt) {
    short8 a  = *(const short8*)(acur + kt * 8192);
    short8 b0 = *(const short8*)(wl + (0 * 32 + kt) * 512);
    short8 b1 = *(const short8*)(wl + (1 * 32 + kt) * 512);
    short8 b2 = *(const short8*)(wl + (2 * 32 + kt) * 512);
    short8 b3 = *(const short8*)(wl + (3 * 32 + kt) * 512);
    a0 = __builtin_amdgcn_mfma_f32_32x32x16_bf16(a, b0, a0, 0, 0, 0);
    a1 = __builtin_amdgcn_mfma_f32_32x32x16_bf16(a, b1, a1, 0, 0, 0);
    a2 = __builtin_amdgcn_mfma_f32_32x32x16_bf16(a, b2, a2, 0, 0, 0);
    a3 = __builtin_amdgcn_mfma_f32_32x32x16_bf16(a, b3, a3, 0, 0, 0);
  }
  acc[0] = a0; acc[1] = a1; acc[2] = a2; acc[3] = a3;
}

// ---------------- cell epilogue for one M-pass (16 cells/lane) ---------------
// rowbase = wv*64 + p*32 + (lane>>5)*4 ; row = rowbase + (r&3) + 8*(r>>2)
__device__ __forceinline__ void cell_epi(
    floatx16 (&acc)[4], float (&crow)[16],
    const float4 (&wi4)[4], const float (&bg)[4],
    const float* xf, int rowbase, int hoff, short* hnxt, short* cxdst)
{
  #pragma unroll
  for (int r = 0; r < 16; ++r) {
    int row = rowbase + (r & 3) + ((r >> 2) << 3);
    float4 xv = *(const float4*)(xf + row * 4);
    float gi = acc[0][r] + wi4[0].x*xv.x + wi4[0].y*xv.y + wi4[0].z*xv.z + wi4[0].w*xv.w + bg[0];
    float gf = acc[1][r] + wi4[1].x*xv.x + wi4[1].y*xv.y + wi4[1].z*xv.z + wi4[1].w*xv.w + bg[1];
    float gg = acc[2][r] + wi4[2].x*xv.x + wi4[2].y*xv.y + wi4[2].z*xv.z + wi4[2].w*xv.w + bg[2];
    float go = acc[3][r] + wi4[3].x*xv.x + wi4[3].y*xv.y + wi4[3].z*xv.z + wi4[3].w*xv.w + bg[3];
    float cn = sigm(gf) * crow[r] + sigm(gi) * tanh_f(gg);
    crow[r] = cn;
    float hv = sigm(go) * tanh_f(cn);
    hnxt[hoff + row * 16] = (short)f2bf(hv);
    if (cxdst) cxdst[r] = (short)f2bf(cn);
  }
}

// ---------------- fused encoder+decoder kernel -------------------------------
__global__ __launch_bounds__(512, 2) void fused_lstm(
    const float* __restrict__ speed, const float* __restrict__ pos,
    const float* __restrict__ Wi_es, const float* __restrict__ b_es,
    const float* __restrict__ Wi_ep, const float* __restrict__ b_ep,
    const float* __restrict__ Wi_ds, const float* __restrict__ b_ds,
    const float* __restrict__ Wi_di, const float* __restrict__ b_di,
    const float* __restrict__ W_fs, const float* __restrict__ b_fs,
    const float* __restrict__ W_fc, const float* __restrict__ b_fc,
    const float* __restrict__ W_emb, const float* __restrict__ b_emb,
    const short* __restrict__ wpack, short* __restrict__ hx,
    short* __restrict__ cx, float* __restrict__ xg,
    int* __restrict__ flags, float* __restrict__ out)
{
  extern __shared__ short lds[];
  short* wlds = lds;                       // 65536 shorts = 131072 B
  float* xf = (float*)(lds + WSLICE);      // 512*4 floats = 8192 B
  int tid = threadIdx.x, lane = tid & 63, wv = tid >> 6;
  int b = blockIdx.x;
  int X = b >> 7, rr = b & 127, G = rr >> 4, j = rr & 15;
  int s = X * 8 + G;
  int rbase = G * 512;
  int* Ps  = flags + s * 16;
  int* FXs = flags + 256 + s * 16;
  short* hxs = hx + (size_t)s * HX_SLOT;
  float* xgs = xg + s * 2048;
  const short* wl = wlds + lane * 8;

  int m31 = lane & 31, half = lane >> 5;
  int col = j * 32 + m31;
  int hoff = (col >> 4) * 8192 + (col & 15);
  int rb0 = wv * 64 + half * 4;            // pass-0 row base
  int rb1 = rb0 + 32;                      // pass-1 row base

  // ---- encoder phase setup ----
  const float* xin = X ? pos : speed;
  float4 wi4[4]; float bg[4];
  {
    const float* Wi = X ? Wi_ep : Wi_es;
    const float* bb = X ? b_ep  : b_es;
    #pragma unroll
    for (int g = 0; g < 4; ++g) {
      wi4[g] = *(const float4*)(Wi + (g * 512 + col) * 4);
      bg[g] = bb[g * 512 + col];
    }
  }
  // LDS weight fill (encoder matrix X, slice j)
  {
    const short* src = wpack + (size_t)(X * 16 + j) * WSLICE;
    for (int i = tid; i < 8192; i += 512)
      *(short8*)(wlds + i * 8) = *(const short8*)(src + i * 8);
  }
  // h(0) = 0: zero own kchunks of parity 0
  {
    short* dst = hxs + j * 16384;          // kchunks 2j,2j+1 contiguous
    for (int i = tid; i < 2048; i += 512) *(short8*)(dst + i * 8) = (short8)0;
  }
  float c0[16], c1[16];
  #pragma unroll
  for (int r = 0; r < 16; ++r) { c0[r] = 0.0f; c1[r] = 0.0f; }
  postflag(Ps + j, 1, tid);                // h(0) published (v1)

  floatx16 acc[4];

  // ---- encoder: 16 steps. h(t) at parity t&1 ----
  for (int t = 0; t < 16; ++t) {
    waitall(Ps, t + 1, tid);
    const short* hcur = hxs + (t & 1) * HX_PAR;
    short* hnxt = hxs + ((t + 1) & 1) * HX_PAR;
    bool fin = (t == 15);
    short* cxme = fin ? (cx + (size_t)b * 16384 + tid * 32) : (short*)0;

    kpass(wl, hcur + (rb0 - half * 4 + m31) * 16 + half * 8, acc);
    // stage x(t) (global -> LDS), then epilogues
    ((float4*)xf)[tid] = *(const float4*)(xin + (size_t)(rbase + tid) * 64 + t * 4);
    __syncthreads();
    cell_epi(acc, c0, wi4, bg, xf, rb0, hoff, hnxt, cxme);
    kpass(wl, hcur + (rb1 - half * 4 + m31) * 16 + half * 8, acc);
    cell_epi(acc, c1, wi4, bg, xf, rb1, hoff, hnxt, fin ? (cxme + 16) : (short*)0);
    postflag(Ps + j, t + 2, tid);          // h(t+1) published
  }

  // ---- handoff: c0 += partner c, h0 = h_se + h_pe -> parity 1 ----
  waitall(Ps, 17, tid);
  {
    int pb = (1 - X) * 128 + (b & 127);
    const short* pcx = cx + (size_t)pb * 16384 + tid * 32;
    #pragma unroll
    for (int r = 0; r < 16; ++r) {
      c0[r] += bf2f((unsigned short)pcx[r]);
      c1[r] += bf2f((unsigned short)pcx[16 + r]);
    }
  }
  {
    const short* hA = hx + (size_t)(0 * 8 + G) * HX_SLOT + j * 16384;
    const short* hB = hx + (size_t)(1 * 8 + G) * HX_SLOT + j * 16384;
    short* hD = hxs + HX_PAR + j * 16384;
    for (int i = tid; i < 16384; i += 512)
      hD[i] = (short)f2bf(bf2f((unsigned short)hA[i]) + bf2f((unsigned short)hB[i]));
  }
  { // x(0) = last observation for this chain's rows slice
    const float* last = X ? pos : speed;
    if (tid < 128) {
      int row = j * 32 + (tid >> 2), c = tid & 3;
      xgs[row * 4 + c] = last[(size_t)(rbase + row) * 64 + 60 + c];
    }
  }
  { // reload LDS weights (decoder matrix 2+X) + decoder Wi/b
    const short* src = wpack + (size_t)((2 + X) * 16 + j) * WSLICE;
    for (int i = tid; i < 8192; i += 512)
      *(short8*)(wlds + i * 8) = *(const short8*)(src + i * 8);
    const float* Wi = X ? Wi_di : Wi_ds;
    const float* bb = X ? b_di  : b_ds;
    #pragma unroll
    for (int g = 0; g < 4; ++g) {
      wi4[g] = *(const float4*)(Wi + (g * 512 + col) * 4);
      bg[g] = bb[g * 512 + col];
    }
  }
  __syncthreads();
  if (tid == 0) {
    __hip_atomic_store(FXs + j, 1, __ATOMIC_RELEASE, __HIP_MEMORY_SCOPE_AGENT);
    __hip_atomic_store(Ps + j, 18, __ATOMIC_RELEASE, __HIP_MEMORY_SCOPE_AGENT);
  }

  // ---- decoder: 32 steps. dec h(t) = version 18+t, parity (t+1)&1 ----
  for (int t = 0; t < 32; ++t) {
    waitall(Ps, 18 + t, tid);
    const short* hcur = hxs + ((t + 1) & 1) * HX_PAR;
    short* hnxt = hxs + (t & 1) * HX_PAR;

    // distributed heads on h(t) (t>=1): output index t-1, feedback x(t)
    if (t >= 1) {
      if (X == 0) {
        float w0[8], w1[8], w2[8], w3[8];
        #pragma unroll
        for (int q = 0; q < 8; ++q) {
          w0[q] = W_fs[lane * 8 + q];        w1[q] = W_fs[512 + lane * 8 + q];
          w2[q] = W_fs[1024 + lane * 8 + q]; w3[q] = W_fs[1536 + lane * 8 + q];
        }
        #pragma unroll 1
        for (int i = 0; i < 4; ++i) {
          int row = j * 32 + wv * 4 + i;
          short8 hv8 = *(const short8*)(hcur + (lane >> 1) * 8192 + row * 16 + (lane & 1) * 8);
          float p0 = 0.f, p1 = 0.f, p2 = 0.f, p3 = 0.f;
          #pragma unroll
          for (int q = 0; q < 8; ++q) {
            float hv = bf2f((unsigned short)hv8[q]);
            p0 += hv * w0[q]; p1 += hv * w1[q]; p2 += hv * w2[q]; p3 += hv * w3[q];
          }
          #pragma unroll
          for (int off = 32; off > 0; off >>= 1) {
            p0 += __shfl_xor(p0, off); p1 += __shfl_xor(p1, off);
            p2 += __shfl_xor(p2, off); p3 += __shfl_xor(p3, off);
          }
          float s0 = fminf(fmaxf(p0 + b_fs[0], -100.0f), 100.0f);
          float s1 = fminf(fmaxf(p1 + b_fs[1], -100.0f), 100.0f);
          float s2 = fminf(fmaxf(p2 + b_fs[2], -100.0f), 100.0f);
          float s3 = fminf(fmaxf(p3 + b_fs[3], -100.0f), 100.0f);
          if (lane < 4) {
            float v = (lane == 0) ? s0 : (lane == 1) ? s1 : (lane == 2) ? s2 : s3;
            out[(size_t)(rbase + row) * 128 + (t - 1) * 4 + lane] = v;
            xgs[row * 4 + lane] = v;
          }
        }
      } else {
        float w0[8], w1[8];
        #pragma unroll
        for (int q = 0; q < 8; ++q) {
          w0[q] = W_fc[lane * 8 + q]; w1[q] = W_fc[512 + lane * 8 + q];
        }
        #pragma unroll 1
        for (int i = 0; i < 4; ++i) {
          int row = j * 32 + wv * 4 + i;
          short8 hv8 = *(const short8*)(hcur + (lane >> 1) * 8192 + row * 16 + (lane & 1) * 8);
          float p0 = 0.f, p1 = 0.f;
          #pragma unroll
          for (int q = 0; q < 8; ++q) {
            float hv = bf2f((unsigned short)hv8[q]);
            p0 += hv * w0[q]; p1 += hv * w1[q];
          }
          #pragma unroll
          for (int off = 32; off > 0; off >>= 1) {
            p0 += __shfl_xor(p0, off); p1 += __shfl_xor(p1, off);
          }
          float it0 = fmaxf(p0 + b_fc[0], 0.0f);
          float it1 = fmaxf(p1 + b_fc[1], 0.0f);
          if (lane < 4) {
            float lp = fmaxf(W_emb[lane * 2] * it0 + W_emb[lane * 2 + 1] * it1 + b_emb[lane], 0.0f);
            xgs[row * 4 + lane] = lp;
          }
        }
      }
      postflag(FXs + j, t + 1, tid);       // x(t) published
    }

    kpass(wl, hcur + (rb0 - half * 4 + m31) * 16 + half * 8, acc);
    waitall(FXs, t + 1, tid);
    ((float4*)xf)[tid] = ((const float4*)xgs)[tid];
    __syncthreads();
    cell_epi(acc, c0, wi4, bg, xf, rb0, hoff, hnxt, (short*)0);
    kpass(wl, hcur + (rb1 - half * 4 + m31) * 16 + half * 8, acc);
    cell_epi(acc, c1, wi4, bg, xf, rb1, hoff, hnxt, (short*)0);
    postflag(Ps + j, 19 + t, tid);
  }

  // ---- final heads on h(32) (parity 1): output index 31 + softmax ----
  waitall(Ps, 50, tid);
  {
    const short* hcur = hxs + HX_PAR;
    if (X == 0) {
      float w0[8], w1[8], w2[8], w3[8];
      #pragma unroll
      for (int q = 0; q < 8; ++q) {
        w0[q] = W_fs[lane * 8 + q];        w1[q] = W_fs[512 + lane * 8 + q];
        w2[q] = W_fs[1024 + lane * 8 + q]; w3[q] = W_fs[1536 + lane * 8 + q];
      }
      #pragma unroll 1
      for (int i = 0; i < 4; ++i) {
        int row = j * 32 + wv * 4 + i;
        short8 hv8 = *(const short8*)(hcur + (lane >> 1) * 8192 + row * 16 + (lane & 1) * 8);
        float p0 = 0.f, p1 = 0.f, p2 = 0.f, p3 = 0.f;
        #pragma unroll
        for (int q = 0; q < 8; ++q) {
          float hv = bf2f((unsigned short)hv8[q]);
          p0 += hv * w0[q]; p1 += hv * w1[q]; p2 += hv * w2[q]; p3 += hv * w3[q];
        }
        #pragma unroll
        for (int off = 32; off > 0; off >>= 1) {
          p0 += __shfl_xor(p0, off); p1 += __shfl_xor(p1, off);
          p2 += __shfl_xor(p2, off); p3 += __shfl_xor(p3, off);
        }
        float s0 = fminf(fmaxf(p0 + b_fs[0], -100.0f), 100.0f);
        float s1 = fminf(fmaxf(p1 + b_fs[1], -100.0f), 100.0f);
        float s2 = fminf(fmaxf(p2 + b_fs[2], -100.0f), 100.0f);
        float s3 = fminf(fmaxf(p3 + b_fs[3], -100.0f), 100.0f);
        if (lane < 4) {
          float v = (lane == 0) ? s0 : (lane == 1) ? s1 : (lane == 2) ? s2 : s3;
          out[(size_t)(rbase + row) * 128 + 31 * 4 + lane] = v;
        }
      }
    } else {
      float w0[8], w1[8];
      #pragma unroll
      for (int q = 0; q < 8; ++q) {
        w0[q] = W_fc[lane * 8 + q]; w1[q] = W_fc[512 + lane * 8 + q];
      }
      #pragma unroll 1
      for (int i = 0; i < 4; ++i) {
        int row = j * 32 + wv * 4 + i;
        short8 hv8 = *(const short8*)(hcur + (lane >> 1) * 8192 + row * 16 + (lane & 1) * 8);
        float p0 = 0.f, p1 = 0.f;
        #pragma unroll
        for (int q = 0; q < 8; ++q) {
          float hv = bf2f((unsigned short)hv8[q]);
          p0 += hv * w0[q]; p1 += hv * w1[q];
        }
        #pragma unroll
        for (int off = 32; off > 0; off >>= 1) {
          p0 += __shfl_xor(p0, off); p1 += __shfl_xor(p1, off);
        }
        float it0 = fmaxf(p0 + b_fc[0], 0.0f);
        float it1 = fmaxf(p1 + b_fc[1], 0.0f);
        if (lane < 2) {
          float m = fmaxf(it0, it1);
          float e0 = __expf(it0 - m), e1 = __expf(it1 - m);
          float v = ((lane == 0) ? e0 : e1) * rcpf(e0 + e1);
          out[(size_t)524288 + (size_t)(rbase + row) * 2 + lane] = v;
        }
      }
    }
  }
}

extern "C" void kernel_launch(void* const* d_in, const int* in_sizes, int n_in,
                              void* d_out, int out_size, void* d_ws, size_t ws_size,
                              hipStream_t stream)
{
  const float* speed    = (const float*)d_in[0];
  const float* pos      = (const float*)d_in[1];
  const float* enc_s_Wi = (const float*)d_in[2];
  const float* enc_s_Wh = (const float*)d_in[3];
  const float* enc_s_b  = (const float*)d_in[4];
  const float* enc_p_Wi = (const float*)d_in[5];
  const float* enc_p_Wh = (const float*)d_in[6];
  const float* enc_p_b  = (const float*)d_in[7];
  const float* dec_s_Wi = (const float*)d_in[8];
  const float* dec_s_Wh = (const float*)d_in[9];
  const float* dec_s_b  = (const float*)d_in[10];
  const float* dec_i_Wi = (const float*)d_in[11];
  const float* dec_i_Wh = (const float*)d_in[12];
  const float* dec_i_b  = (const float*)d_in[13];
  const float* W_fs     = (const float*)d_in[14];
  const float* b_fs     = (const float*)d_in[15];
  const float* W_fc     = (const float*)d_in[16];
  const float* b_fc     = (const float*)d_in[17];
  const float* W_emb    = (const float*)d_in[18];
  const float* b_emb    = (const float*)d_in[19];
  float* out = (float*)d_out;

  char* ws = (char*)d_ws;
  short* wpack = (short*)ws;                       //  8,388,608 B
  short* hx    = (short*)(ws + 8388608);           // 16,777,216 B (16 slots x 2 par)
  short* cx    = (short*)(ws + 25165824);          //  8,388,608 B (256 blk x 16384 bf16)
  float* xg    = (float*)(ws + 33554432);          //    131,072 B (16 x 512 x 4)
  int*   flags = (int*)(ws + 33685504);            //      4,096 B

  const int dynLDS = WSLICE * 2 + 512 * 4 * 4;     // 139,264 B
  hipFuncSetAttribute((const void*)fused_lstm,
                      hipFuncAttributeMaxDynamicSharedMemorySize, dynLDS);

  prep_weights<<<16384, 256, 0, stream>>>(
      enc_s_Wh, enc_p_Wh, dec_s_Wh, dec_i_Wh, wpack, flags);
  fused_lstm<<<256, 512, dynLDS, stream>>>(
      speed, pos,
      enc_s_Wi, enc_s_b, enc_p_Wi, enc_p_b,
      dec_s_Wi, dec_s_b, dec_i_Wi, dec_i_b,
      W_fs, b_fs, W_fc, b_fc, W_emb, b_emb,
      wpack, hx, cx, xg, flags, out);
}